// Round 17
// baseline (11376.025 us; speedup 1.0000x reference)
//
#include <hip/hip_runtime.h>
#include <cstddef>

#define BB 32
#define TT 512
#define HH 512
#define NBLK 512
#define NTHR 512
#define YD 16  // y0 ring depth
#define AG __HIP_MEMORY_SCOPE_AGENT

// ---------------------------------------------------------------------------
// Persistent GRU, round 16 = round 15 (co-located layers) + EARLY-CLOBBER fix
// on all multi-load inline asm ("=&v"): without it, LLVM may alias a load's
// DEST register pair with a later load's ADDRESS pair (asm outputs are
// assumed written after all inputs are read — false for async loads). That
// aliasing is the diagnosed cause of round-15's GPU memory fault.
//
// Design (round 15): 512 blocks x 512 thr, launch_bounds(512,4) -> 128-VGPR
// cap, 2 blocks/CU, grid == capacity -> all resident. Each XCD: 64 blocks =
// 32 L0 + 32 L1 of ONE batch-group (4 batches). ALL state (h/rh/uu/y0) and
// ALL flags XCD-local: plain stores + sc0 loads (round-6-proven). sc1 only
// as flag mirror (every-8-spin truth mix-in) and fallback. While one layer
// waits, the co-resident other-layer block computes (TLP hides barriers).
//
// Sync protocol (r13/r14 proven): slot-as-progress flags, ballot polls,
// arrive = syncthreads (vmcnt drain) + flag stores. Gates: L1 A(t): peer >=
// 2t+2; L0 B(t>=YD): peer >= 2t-31; own: 2t / 2t+1. Arrivals unconditional
// incl. last phase -> no deadlock. Fallback (bad XCC map): all sc1.
//
// ws (floats): h@0 [2*8][4][512]=32768, ctrl(int)@32768[64],
//   barb(int)@32832[192], gslot(int)@33024[16*32], lslot(int)@33536[16*32]
//   (zero region ends @34048)
//   y0@36864[16][32][512], rh@299008[2*8][4][512], uu@331776[2*8][4][512]
// ---------------------------------------------------------------------------

__device__ __forceinline__ float2 ld2_sc1(const float* p) {
    double d = __hip_atomic_load((const double*)p, __ATOMIC_RELAXED, AG);
    return __builtin_bit_cast(float2, d);
}
__device__ __forceinline__ float ld1f_sc1(const float* p) {
    return __hip_atomic_load(p, __ATOMIC_RELAXED, AG);
}
__device__ __forceinline__ void st1_sc1(float* p, float v) {
    __hip_atomic_store(p, v, __ATOMIC_RELAXED, AG);
}
__device__ __forceinline__ int ldi_sc1(const int* p) {
    return __hip_atomic_load(p, __ATOMIC_RELAXED, AG);
}
__device__ __forceinline__ void sti_sc1(int* p, int v) {
    __hip_atomic_store(p, v, __ATOMIC_RELAXED, AG);
}
// Plain store: dirty in the local XCD L2 (round-6 data-store mechanism).
__device__ __forceinline__ void sti_plain(int* p, int v) {
    asm volatile("global_store_dword %0, %1, off" : : "v"(p), "v"(v) : "memory");
}
// L1-bypassing scalar int load served by the local L2 (early-clobber dest).
__device__ __forceinline__ int ldi_sc0(const int* p) {
    int r;
    asm volatile("global_load_dword %0, %1, off sc0\n\ts_waitcnt vmcnt(0)"
                 : "=&v"(r) : "v"(p) : "memory");
    return r;
}
// Scalar float load, L1-bypass / local-L2 hit (early-clobber dest).
__device__ __forceinline__ float ld_sc0f(const float* p) {
    float r;
    asm volatile("global_load_dword %0, %1, off sc0\n\ts_waitcnt vmcnt(0)"
                 : "=&v"(r) : "v"(p) : "memory");
    return r;
}
// Packed f32 FMA: 2 FMAs in one instruction (issue-bound win, r13-proven).
__device__ __forceinline__ float2 pkfma(float2 a, float2 b, float2 c) {
    float2 d;
    asm("v_pk_fma_f32 %0, %1, %2, %3" : "=v"(d) : "v"(a), "v"(b), "v"(c));
    return d;
}
// Four 8B loads, L1-bypass / local-L2 hit. EARLY-CLOBBER outputs: dest pairs
// must never alias later loads' address pairs (async writeback hazard).
__device__ __forceinline__ void ld2_sc0_x4(const float* p0, const float* p1,
                                           const float* p2, const float* p3,
                                           float2& v0, float2& v1,
                                           float2& v2, float2& v3) {
    asm volatile(
        "global_load_dwordx2 %0, %4, off sc0\n\t"
        "global_load_dwordx2 %1, %5, off sc0\n\t"
        "global_load_dwordx2 %2, %6, off sc0\n\t"
        "global_load_dwordx2 %3, %7, off sc0\n\t"
        "s_waitcnt vmcnt(0)"
        : "=&v"(v0), "=&v"(v1), "=&v"(v2), "=&v"(v3)
        : "v"(p0), "v"(p1), "v"(p2), "v"(p3)
        : "memory");
}

// Reduce 4 accs over 64 lanes; lane ends with total of acc[lane&3].
__device__ __forceinline__ float red4(float a0, float a1, float a2, float a3,
                                      int lane) {
    const bool b1 = lane & 1, b2 = lane & 2;
    float p0 = (b1 ? a1 : a0) + __shfl_xor((b1 ? a0 : a1), 1, 64);
    float p1 = (b1 ? a3 : a2) + __shfl_xor((b1 ? a2 : a3), 1, 64);
    float r = (b2 ? p1 : p0) + __shfl_xor((b2 ? p0 : p1), 2, 64);
    r += __shfl_xor(r, 4, 64);
    r += __shfl_xor(r, 8, 64);
    r += __shfl_xor(r, 16, 64);
    r += __shfl_xor(r, 32, 64);
    return r;
}
// Reduce 2 accs; lane ends with total of acc[lane&1].
__device__ __forceinline__ float red2(float a0, float a1, int lane) {
    const bool b1 = lane & 1;
    float r = (b1 ? a1 : a0) + __shfl_xor((b1 ? a0 : a1), 1, 64);
    r += __shfl_xor(r, 2, 64);
    r += __shfl_xor(r, 4, 64);
    r += __shfl_xor(r, 8, 64);
    r += __shfl_xor(r, 16, 64);
    r += __shfl_xor(r, 32, 64);
    return r;
}

// Global 2-level tree barrier (sc1 RMW) — prologue only (512 blocks:
// 32 leaves x 16 arrivals, 32 root adders).
__device__ __forceinline__ void gbar(int* barb, int bid, int nbar) {
    __syncthreads();
    if (threadIdx.x == 0) {
        __hip_atomic_fetch_add(&barb[(bid & 31) * 4], 1, __ATOMIC_RELAXED, AG);
        if (bid < 32) {
            const int lt = nbar * 16;
            while (__hip_atomic_load(&barb[bid * 4], __ATOMIC_RELAXED, AG) < lt)
                __builtin_amdgcn_s_sleep(1);
            __hip_atomic_fetch_add(&barb[128], 1, __ATOMIC_RELAXED, AG);
        }
        const int rt = nbar * 32;
        while (__hip_atomic_load(&barb[128], __ATOMIC_RELAXED, AG) < rt)
            __builtin_amdgcn_s_sleep(1);
    }
    __syncthreads();
}

// Group poll: local-L2 sc0 fast path + every-8th-spin sc1 truth mix-in.
template <int SLP>
__device__ __forceinline__ void poll_grp(int* larr, int* garr, int need, int fb) {
    if (threadIdx.x < 64) {
        const int L = threadIdx.x & 31;
        int spins = 0;
        for (;;) {
            int v;
            if (fb) {
                v = ldi_sc1(&garr[L]);
            } else {
                v = ldi_sc0(&larr[L]);
                if ((spins & 7) == 7) {
                    const int gv = ldi_sc1(&garr[L]);
                    v = v > gv ? v : gv;
                }
            }
            if (__ballot(v >= need) == ~0ull) break;
            ++spins;
            __builtin_amdgcn_s_sleep(SLP);
        }
    }
    __syncthreads();
}

// Arrive: drain block stores, then dual flag store (local plain + global sc1).
__device__ __forceinline__ void arrive(int* lslot, int* gslot, int val, int fb) {
    __syncthreads();  // compiler drains vmcnt(0) before s_barrier
    if (threadIdx.x == 0) {
        if (!fb) sti_plain(lslot, val);
        sti_sc1(gslot, val);
    }
}

__global__ __launch_bounds__(NTHR, 4) void rnn_persist(
    const float* __restrict__ x, const int* __restrict__ seq_lens,
    const float* __restrict__ Wg, const float* __restrict__ bg,
    const float* __restrict__ Wc, const float* __restrict__ bc,
    float* __restrict__ out, float* __restrict__ ws) {
    __shared__ float ldsA[4][1024];  // per batch: [input 512 | h 512]
    __shared__ float ldsB[4][512];   // rh rows
    __shared__ float ldsU[4][16];    // u, block's own 16 cand cols only
    __shared__ int shi[4];

    int* ctrl = (int*)(ws + 32768);   // pools[16], nlab@16, fb@17, map@18..33
    int* barb = (int*)(ws + 32832);   // global tree (prologue only)
    int* gslot = (int*)(ws + 33024);  // 16 groups x 32 ints (sc1 mirror)
    int* lslot = (int*)(ws + 33536);  // 16 groups x 32 ints (local flags)
    float* y0b = ws + 36864;          // [16][32][512]

    const int tid = threadIdx.x, bid = blockIdx.x;
    const int w = tid >> 6, lane = tid & 63;

    // ---- self-organization by physical XCD: expect 8 pools of 64 ----
    if (tid == 0) {
        int xcc;
        asm volatile("s_getreg_b32 %0, hwreg(HW_REG_XCC_ID)" : "=s"(xcc));
        xcc &= 15;
        int s64 = __hip_atomic_fetch_add(&ctrl[xcc], 1, __ATOMIC_RELAXED, AG);
        shi[0] = xcc; shi[1] = s64;
    }
    __syncthreads();
    gbar(barb, bid, 1);
    if (tid == 0) {
        if (ldi_sc1(&ctrl[shi[0]]) != 64)
            sti_sc1(&ctrl[17], 1);
        if (shi[1] == 0) {
            int ord = __hip_atomic_fetch_add(&ctrl[16], 1, __ATOMIC_RELAXED, AG);
            sti_sc1(&ctrl[18 + shi[0]], ord + 1);
        }
    }
    gbar(barb, bid, 2);
    if (tid == 0) {
        int fbf = ldi_sc1(&ctrl[17]);
        if (ldi_sc1(&ctrl[16]) != 8) fbf = 1;
        int xi, s64;
        if (fbf) { xi = bid & 7; s64 = bid >> 3; }
        else     { xi = ldi_sc1(&ctrl[18 + shi[0]]) - 1; s64 = shi[1]; }
        shi[2] = fbf; shi[3] = xi; shi[1] = s64;
    }
    __syncthreads();
    const int fb = shi[2];
    const int g = shi[3];          // batch group 0..7 (== XCD in happy path)
    const int s64 = shi[1];        // 0..63 within XCD
    const int l = s64 & 1;         // layer
    const int slot = s64 >> 1;     // 0..31 within (XCD, layer) group
    const int b0 = g * 4;          // batches [b0, b0+4)
    const int gj0 = slot * 32 + w * 4;
    const int cm0 = slot * 16 + w * 2;
    const int kb = 2 * lane;
    const int fg = (g << 1) | l;

    float* __restrict__ hb  = ws + (size_t)(l * 8 + g) * (4 * HH);
    float* __restrict__ rhb = ws + 299008 + (size_t)(l * 8 + g) * (4 * HH);
    float* __restrict__ uub = ws + 331776 + (size_t)(l * 8 + g) * (4 * HH);
    int* lmy = lslot + fg * 32;
    int* gmy = gslot + fg * 32;
    int* lpeer = lslot + (fg ^ 1) * 32;
    int* gpeer = gslot + (fg ^ 1) * 32;

    // ---- one-time weight load into registers (original layout) ----
    float2 wg[4][8];
#pragma unroll
    for (int c = 0; c < 4; ++c)
#pragma unroll
        for (int i = 0; i < 8; ++i) {
            const size_t r = (size_t)l * 1024 + kb + (i << 7);
            wg[c][i].x = Wg[r * 1024 + gj0 + c];
            wg[c][i].y = Wg[(r + 1) * 1024 + gj0 + c];
        }
    float2 wc[2][8];
#pragma unroll
    for (int c = 0; c < 2; ++c)
#pragma unroll
        for (int i = 0; i < 8; ++i) {
            const size_t r = (size_t)l * 1024 + kb + (i << 7);
            wc[c][i].x = Wc[r * 512 + cm0 + c];
            wc[c][i].y = Wc[(r + 1) * 512 + cm0 + c];
        }
    const float bgj = bg[l * 1024 + gj0 + (lane & 3)];
    const float bcm = bc[l * 512 + cm0 + (lane & 1)];
    int sl_[4];
#pragma unroll
    for (int i = 0; i < 4; ++i) sl_[i] = seq_lens[b0 + i];

    for (int t = 0; t < TT; ++t) {
        // ================= phase A: gates =================
        // L1 gate: y0[t] produced <=> all L0 slots >= 2t+2.
        if (l == 1) poll_grp<2>(lpeer, gpeer, 2 * t + 2, fb);
        // stage in-rows (waves 0-3; no own-group dependency)
        if (w < 4) {
            const int bi = w;
            const float* inrow = l ? (y0b + ((size_t)((t & (YD - 1)) * 32 + b0 + bi)) * HH)
                                   : (x + ((size_t)(b0 + bi) * TT + t) * HH);
            float2 vi[4];
            if (l == 0) {
#pragma unroll
                for (int i = 0; i < 4; ++i)
                    vi[i] = *(const float2*)(inrow + kb + (i << 7));
            } else if (fb) {
#pragma unroll
                for (int i = 0; i < 4; ++i)
                    vi[i] = ld2_sc1(inrow + kb + (i << 7));
            } else {
                ld2_sc0_x4(inrow + kb, inrow + kb + 128, inrow + kb + 256,
                           inrow + kb + 384, vi[0], vi[1], vi[2], vi[3]);
            }
#pragma unroll
            for (int i = 0; i < 4; ++i)
                *(float2*)&ldsA[bi][kb + (i << 7)] = vi[i];
        }
        // wait end-of-B(t-1): h(t) final, rh/uu(t-1) consumed
        if (t > 0) poll_grp<1>(lmy, gmy, 2 * t, fb);
        // stage h-rows (waves 4-7, fresh after wait)
        if (w >= 4) {
            const int bi = w - 4;
            const float* hrow = hb + (size_t)bi * HH;
            float2 vh[4];
            if (fb) {
#pragma unroll
                for (int i = 0; i < 4; ++i)
                    vh[i] = ld2_sc1(hrow + kb + (i << 7));
            } else {
                ld2_sc0_x4(hrow + kb, hrow + kb + 128, hrow + kb + 256,
                           hrow + kb + 384, vh[0], vh[1], vh[2], vh[3]);
            }
#pragma unroll
            for (int i = 0; i < 4; ++i)
                *(float2*)&ldsA[bi][512 + kb + (i << 7)] = vh[i];
        }
        __syncthreads();
#pragma unroll
        for (int bi = 0; bi < 4; ++bi) {
            float2 q0 = {0.f, 0.f}, q1 = {0.f, 0.f}, q2 = {0.f, 0.f}, q3 = {0.f, 0.f};
#pragma unroll
            for (int i = 0; i < 8; ++i) {
                const float2 v = *(const float2*)&ldsA[bi][kb + (i << 7)];
                q0 = pkfma(v, wg[0][i], q0);
                q1 = pkfma(v, wg[1][i], q1);
                q2 = pkfma(v, wg[2][i], q2);
                q3 = pkfma(v, wg[3][i], q3);
            }
            const float sum = red4(q0.x + q0.y, q1.x + q1.y,
                                   q2.x + q2.y, q3.x + q3.y, lane);
            if (lane < 4) {
                const int j = gj0 + lane;
                const float gg = 1.0f / (1.0f + __expf(-(sum + bgj)));
                if (gj0 < HH) {
                    const float val = gg * ldsA[bi][512 + j];
                    if (fb) st1_sc1(rhb + (size_t)bi * HH + j, val);
                    else rhb[(size_t)bi * HH + j] = val;
                } else {
                    if (fb) st1_sc1(uub + (size_t)bi * HH + (j - HH), gg);
                    else uub[(size_t)bi * HH + (j - HH)] = gg;
                }
            }
        }
        arrive(&lmy[slot], &gmy[slot], 2 * t + 1, fb);

        // ================= phase B: candidate + update =================
        // cand x-half partials (from ldsA in-half; overlaps peers' A-finish)
        float2 pB0[4], pB1[4];
#pragma unroll
        for (int bi = 0; bi < 4; ++bi) {
            float2 q0 = {0.f, 0.f}, q1 = {0.f, 0.f};
#pragma unroll
            for (int i = 0; i < 4; ++i) {
                const float2 v = *(const float2*)&ldsA[bi][kb + (i << 7)];
                q0 = pkfma(v, wc[0][i], q0);
                q1 = pkfma(v, wc[1][i], q1);
            }
            pB0[bi] = q0; pB1[bi] = q1;
        }
        // wait end-of-A(t): rh/uu(t) ready, h(t) consumed
        poll_grp<1>(lmy, gmy, 2 * t + 1, fb);
        // L0 ring gate: L1 consumed y0[t-16] <=> all L1 slots >= 2t-31.
        if (l == 0 && t >= YD) poll_grp<2>(lpeer, gpeer, 2 * t - 31, fb);
        // stage rh rows (waves 0-3) + u own-cols (waves 4-7)
        if (w < 4) {
            const int bi = w;
            const float* rrow = rhb + (size_t)bi * HH;
            float2 vr[4];
            if (fb) {
#pragma unroll
                for (int i = 0; i < 4; ++i)
                    vr[i] = ld2_sc1(rrow + kb + (i << 7));
            } else {
                ld2_sc0_x4(rrow + kb, rrow + kb + 128, rrow + kb + 256,
                           rrow + kb + 384, vr[0], vr[1], vr[2], vr[3]);
            }
#pragma unroll
            for (int i = 0; i < 4; ++i)
                *(float2*)&ldsB[bi][kb + (i << 7)] = vr[i];
        } else if (lane < 16) {
            const int bi = w - 4;
            const float* up = uub + (size_t)bi * HH + slot * 16 + lane;
            ldsU[bi][lane] = fb ? ld1f_sc1(up) : ld_sc0f(up);
        }
        __syncthreads();
#pragma unroll
        for (int bi = 0; bi < 4; ++bi) {
            float2 q0 = pB0[bi], q1 = pB1[bi];
#pragma unroll
            for (int i = 0; i < 4; ++i) {
                const float2 v = *(const float2*)&ldsB[bi][kb + (i << 7)];
                q0 = pkfma(v, wc[0][i + 4], q0);
                q1 = pkfma(v, wc[1][i + 4], q1);
            }
            const float sum = red2(q0.x + q0.y, q1.x + q1.y, lane);
            if (lane < 2) {
                const int m = cm0 + lane;
                const int b = b0 + bi;
                const float cv = tanhf(sum + bcm);
                const float u = ldsU[bi][w * 2 + lane];
                const float hold = ldsA[bi][512 + m];
                const bool act = t < sl_[bi];
                const float hn = u * hold + (1.0f - u) * cv;
                const float hstore = act ? hn : hold;
                if (fb) st1_sc1(hb + (size_t)bi * HH + m, hstore);
                else hb[(size_t)bi * HH + m] = hstore;
                const float yv = act ? hn : 0.0f;
                if (l == 0) {
                    float* yp = y0b + ((size_t)((t & (YD - 1)) * 32 + b)) * HH + m;
                    if (fb) st1_sc1(yp, yv);
                    else *yp = yv;
                } else {
                    out[((size_t)b * TT + t) * HH + m] = yv;
                }
            }
        }
        arrive(&lmy[slot], &gmy[slot], 2 * t + 2, fb);
    }
}

extern "C" void kernel_launch(void* const* d_in, const int* in_sizes, int n_in,
                              void* d_out, int out_size, void* d_ws, size_t ws_size,
                              hipStream_t stream) {
    const float* x = (const float*)d_in[0];
    const int* seq_lens = (const int*)d_in[1];
    const float* Wg = (const float*)d_in[2];
    const float* bg = (const float*)d_in[3];
    const float* Wc = (const float*)d_in[4];
    const float* bc = (const float*)d_in[5];
    float* out = (float*)d_out;
    float* ws = (float*)d_ws;

    // zero h + ctrl + prologue tree + both flag arrays every launch
    (void)hipMemsetAsync(ws, 0, 34048 * sizeof(float), stream);

    rnn_persist<<<NBLK, NTHR, 0, stream>>>(x, seq_lens, Wg, bg, Wc, bc, out, ws);
}

// Round 18
// 6983.887 us; speedup vs baseline: 1.6289x; 1.6289x over previous
//
#include <hip/hip_runtime.h>
#include <cstddef>

#define BB 32
#define TT 512
#define HH 512
#define NBLK 256
#define NTHR 512
#define AG __HIP_MEMORY_SCOPE_AGENT

// ---------------------------------------------------------------------------
// Persistent GRU, round 17: BOTH LAYERS FOLDED INTO EACH BLOCK on the proven
// 256-block / 1-block-per-CU mapping (r6-r14: pools of 32 per XCD, reliable).
//
//   XCD = batch-group g (4 batches), both layers. Block slot s (0..31):
//   gate cols [32s,32s+32) and cand cols [16s,16s+16) for L0@t AND L1@(t-1).
//   Same dots/block as r13; 2 group barriers/step; NO peer polls, NO ring
//   gates, NO sc1 data: y0 is a group-internal buffer (write B(t), read
//   A(t+1) -- the own barriers order it; single buffer WAR-safe).
//   Group early-exit: T_g = max(seq_len of the 4 batches); loop t=0..T_g.
//   t>=T_g output is pre-zeroed by hipMemsetAsync(d_out). Masked steps
//   (len_b <= t < T_g) freeze h and write y=0 exactly like the reference.
//
//   Data: all state plain stores + sc0 loads (XCD-local L2, r6-proven);
//   x/W/b plain cached. Flags: dual local-plain + sc1 mirror with every-8
//   spin truth mix-in (r14-proven). Fallback (bad XCC map): everything sc1.
//   Liveness: arrivals unconditional every phase; waits only on own group's
//   past arrivals; groups fully independent -> no cross-group waits at all.
//
// ws (floats): h[2][8][4][512]@0 (l=1 at 16384), rh@32768 (l=1 @49152),
//   uu@65536 (l=1 @81920), y0[8][4][512]@98304,
//   ctrl(int)@114688[64], barb(int)@114752[192],
//   gslot(int)@114944[8*32], lslot(int)@115200[8*32]  (zero end @115456)
// ---------------------------------------------------------------------------

__device__ __forceinline__ float2 ld2_sc1(const float* p) {
    double d = __hip_atomic_load((const double*)p, __ATOMIC_RELAXED, AG);
    return __builtin_bit_cast(float2, d);
}
__device__ __forceinline__ float ld1f_sc1(const float* p) {
    return __hip_atomic_load(p, __ATOMIC_RELAXED, AG);
}
__device__ __forceinline__ void st1_sc1(float* p, float v) {
    __hip_atomic_store(p, v, __ATOMIC_RELAXED, AG);
}
__device__ __forceinline__ int ldi_sc1(const int* p) {
    return __hip_atomic_load(p, __ATOMIC_RELAXED, AG);
}
__device__ __forceinline__ void sti_sc1(int* p, int v) {
    __hip_atomic_store(p, v, __ATOMIC_RELAXED, AG);
}
// Plain store: dirty in the local XCD L2 (round-6 data-store mechanism).
__device__ __forceinline__ void sti_plain(int* p, int v) {
    asm volatile("global_store_dword %0, %1, off" : : "v"(p), "v"(v) : "memory");
}
// L1-bypassing loads served by the local L2 (early-clobber dests, r16 fix).
__device__ __forceinline__ int ldi_sc0(const int* p) {
    int r;
    asm volatile("global_load_dword %0, %1, off sc0\n\ts_waitcnt vmcnt(0)"
                 : "=&v"(r) : "v"(p) : "memory");
    return r;
}
__device__ __forceinline__ float ld_sc0f(const float* p) {
    float r;
    asm volatile("global_load_dword %0, %1, off sc0\n\ts_waitcnt vmcnt(0)"
                 : "=&v"(r) : "v"(p) : "memory");
    return r;
}
// Packed f32 FMA (issue-bound win, r13-proven).
__device__ __forceinline__ float2 pkfma(float2 a, float2 b, float2 c) {
    float2 d;
    asm("v_pk_fma_f32 %0, %1, %2, %3" : "=v"(d) : "v"(a), "v"(b), "v"(c));
    return d;
}
// Four 8B loads, L1-bypass / local-L2 hit, EARLY-CLOBBER outputs (r16 fix).
__device__ __forceinline__ void ld2_sc0_x4(const float* p0, const float* p1,
                                           const float* p2, const float* p3,
                                           float2& v0, float2& v1,
                                           float2& v2, float2& v3) {
    asm volatile(
        "global_load_dwordx2 %0, %4, off sc0\n\t"
        "global_load_dwordx2 %1, %5, off sc0\n\t"
        "global_load_dwordx2 %2, %6, off sc0\n\t"
        "global_load_dwordx2 %3, %7, off sc0\n\t"
        "s_waitcnt vmcnt(0)"
        : "=&v"(v0), "=&v"(v1), "=&v"(v2), "=&v"(v3)
        : "v"(p0), "v"(p1), "v"(p2), "v"(p3)
        : "memory");
}

// Reduce 4 accs over 64 lanes; lane ends with total of acc[lane&3].
__device__ __forceinline__ float red4(float a0, float a1, float a2, float a3,
                                      int lane) {
    const bool b1 = lane & 1, b2 = lane & 2;
    float p0 = (b1 ? a1 : a0) + __shfl_xor((b1 ? a0 : a1), 1, 64);
    float p1 = (b1 ? a3 : a2) + __shfl_xor((b1 ? a2 : a3), 1, 64);
    float r = (b2 ? p1 : p0) + __shfl_xor((b2 ? p0 : p1), 2, 64);
    r += __shfl_xor(r, 4, 64);
    r += __shfl_xor(r, 8, 64);
    r += __shfl_xor(r, 16, 64);
    r += __shfl_xor(r, 32, 64);
    return r;
}
// Reduce 2 accs; lane ends with total of acc[lane&1].
__device__ __forceinline__ float red2(float a0, float a1, int lane) {
    const bool b1 = lane & 1;
    float r = (b1 ? a1 : a0) + __shfl_xor((b1 ? a0 : a1), 1, 64);
    r += __shfl_xor(r, 2, 64);
    r += __shfl_xor(r, 4, 64);
    r += __shfl_xor(r, 8, 64);
    r += __shfl_xor(r, 16, 64);
    r += __shfl_xor(r, 32, 64);
    return r;
}

// Global 2-level tree barrier (sc1 RMW) — prologue / self-org only (proven).
__device__ __forceinline__ void gbar(int* barb, int bid, int nbar) {
    __syncthreads();
    if (threadIdx.x == 0) {
        __hip_atomic_fetch_add(&barb[(bid & 31) * 4], 1, __ATOMIC_RELAXED, AG);
        if (bid < 32) {
            const int lt = nbar * 8;
            while (__hip_atomic_load(&barb[bid * 4], __ATOMIC_RELAXED, AG) < lt)
                __builtin_amdgcn_s_sleep(1);
            __hip_atomic_fetch_add(&barb[128], 1, __ATOMIC_RELAXED, AG);
        }
        const int rt = nbar * 32;
        while (__hip_atomic_load(&barb[128], __ATOMIC_RELAXED, AG) < rt)
            __builtin_amdgcn_s_sleep(1);
    }
    __syncthreads();
}

// Own-group poll: local sc0 fast path + every-8th-spin sc1 truth (r14-proven).
template <int SLP>
__device__ __forceinline__ void poll_own(int* lown, int* gown, int need, int fb) {
    if (threadIdx.x < 64) {
        const int L = threadIdx.x & 31;
        int spins = 0;
        for (;;) {
            int v;
            if (fb) {
                v = ldi_sc1(&gown[L]);
            } else {
                v = ldi_sc0(&lown[L]);
                if ((spins & 7) == 7) {
                    const int gv = ldi_sc1(&gown[L]);
                    v = v > gv ? v : gv;
                }
            }
            if (__ballot(v >= need) == ~0ull) break;
            ++spins;
            __builtin_amdgcn_s_sleep(SLP);
        }
    }
    __syncthreads();
}

// Arrive: drain block stores, then dual flag store (local plain + sc1 mirror).
__device__ __forceinline__ void arrive(int* lslot, int* gslot, int val, int fb) {
    __syncthreads();  // compiler drains vmcnt(0) before s_barrier
    if (threadIdx.x == 0) {
        if (!fb) sti_plain(lslot, val);
        sti_sc1(gslot, val);
    }
}

__global__ __launch_bounds__(NTHR, 2) void rnn_persist(
    const float* __restrict__ x, const int* __restrict__ seq_lens,
    const float* __restrict__ Wg, const float* __restrict__ bg,
    const float* __restrict__ Wc, const float* __restrict__ bc,
    float* __restrict__ out, float* __restrict__ ws) {
    __shared__ float ldsA[2][4][1024];  // [layer][batch][in 512 | h 512]
    __shared__ float ldsB[2][4][512];   // rh rows
    __shared__ float ldsU[2][4][16];    // u, block's own 16 cand cols
    __shared__ int shi[4];

    int* ctrl = (int*)(ws + 114688);
    int* barb = (int*)(ws + 114752);
    int* gslot = (int*)(ws + 114944);
    int* lslot = (int*)(ws + 115200);

    const int tid = threadIdx.x, bid = blockIdx.x;
    const int w = tid >> 6, lane = tid & 63;

    // ---- self-organization by physical XCD: 8 pools of 32 (proven) ----
    if (tid == 0) {
        int xcc;
        asm volatile("s_getreg_b32 %0, hwreg(HW_REG_XCC_ID)" : "=s"(xcc));
        xcc &= 15;
        int slot = __hip_atomic_fetch_add(&ctrl[xcc], 1, __ATOMIC_RELAXED, AG);
        shi[0] = xcc; shi[1] = slot;
    }
    __syncthreads();
    gbar(barb, bid, 1);
    if (tid == 0) {
        if (ldi_sc1(&ctrl[shi[0]]) != 32)
            sti_sc1(&ctrl[17], 1);
        if (shi[1] == 0) {
            int ord = __hip_atomic_fetch_add(&ctrl[16], 1, __ATOMIC_RELAXED, AG);
            sti_sc1(&ctrl[18 + shi[0]], ord + 1);
        }
    }
    gbar(barb, bid, 2);
    if (tid == 0) {
        int fbf = ldi_sc1(&ctrl[17]);
        if (ldi_sc1(&ctrl[16]) != 8) fbf = 1;
        int xi, sl;
        if (fbf) { xi = bid & 7; sl = bid >> 3; }
        else     { xi = ldi_sc1(&ctrl[18 + shi[0]]) - 1; sl = shi[1]; }
        shi[2] = fbf; shi[3] = xi; shi[1] = sl;
    }
    __syncthreads();
    const int fb = shi[2];
    const int g = shi[3];     // batch group / XCD 0..7
    const int slot = shi[1];  // 0..31 within group
    const int b0 = g * 4;
    const int gj0 = slot * 32 + w * 4;
    const int cm0 = slot * 16 + w * 2;
    const int kb = 2 * lane;

    float* __restrict__ h0b = ws + (size_t)g * 2048;
    float* __restrict__ h1b = ws + 16384 + (size_t)g * 2048;
    float* __restrict__ rh0 = ws + 32768 + (size_t)g * 2048;
    float* __restrict__ rh1 = ws + 49152 + (size_t)g * 2048;
    float* __restrict__ uu0 = ws + 65536 + (size_t)g * 2048;
    float* __restrict__ uu1 = ws + 81920 + (size_t)g * 2048;
    float* __restrict__ y0g = ws + 98304 + (size_t)g * 2048;
    int* lmy = lslot + g * 32;
    int* gmy = gslot + g * 32;

    // ---- one-time weight load: BOTH layers resident (192 floats/lane) ----
    float2 wg0[4][8], wg1[4][8];
#pragma unroll
    for (int c = 0; c < 4; ++c)
#pragma unroll
        for (int i = 0; i < 8; ++i) {
            const size_t r0 = (size_t)(kb + (i << 7));
            wg0[c][i].x = Wg[r0 * 1024 + gj0 + c];
            wg0[c][i].y = Wg[(r0 + 1) * 1024 + gj0 + c];
            const size_t r1 = (size_t)(1024 + kb + (i << 7));
            wg1[c][i].x = Wg[r1 * 1024 + gj0 + c];
            wg1[c][i].y = Wg[(r1 + 1) * 1024 + gj0 + c];
        }
    float2 wc0[2][8], wc1[2][8];
#pragma unroll
    for (int c = 0; c < 2; ++c)
#pragma unroll
        for (int i = 0; i < 8; ++i) {
            const size_t r0 = (size_t)(kb + (i << 7));
            wc0[c][i].x = Wc[r0 * 512 + cm0 + c];
            wc0[c][i].y = Wc[(r0 + 1) * 512 + cm0 + c];
            const size_t r1 = (size_t)(1024 + kb + (i << 7));
            wc1[c][i].x = Wc[r1 * 512 + cm0 + c];
            wc1[c][i].y = Wc[(r1 + 1) * 512 + cm0 + c];
        }
    const float bg0 = bg[gj0 + (lane & 3)];
    const float bg1 = bg[1024 + gj0 + (lane & 3)];
    const float bc0 = bc[cm0 + (lane & 1)];
    const float bc1 = bc[512 + cm0 + (lane & 1)];
    int sl_[4];
#pragma unroll
    for (int i = 0; i < 4; ++i) sl_[i] = seq_lens[b0 + i];
    int Tg = sl_[0];
#pragma unroll
    for (int i = 1; i < 4; ++i) Tg = sl_[i] > Tg ? sl_[i] : Tg;

    for (int t = 0; t <= Tg; ++t) {
        const bool a0 = (t < Tg);
        const bool a1 = (t >= 1);
        const int tt = t - 1;

        // ================= phase A: gates (L0@t, L1@tt) =================
        if (a0 && w < 4) {  // x rows (immutable) — staged before the wait
            const int bi = w;
            const float* inrow = x + ((size_t)(b0 + bi) * TT + t) * HH;
            float2 vi[4];
#pragma unroll
            for (int i = 0; i < 4; ++i)
                vi[i] = *(const float2*)(inrow + kb + (i << 7));
#pragma unroll
            for (int i = 0; i < 4; ++i)
                *(float2*)&ldsA[0][bi][kb + (i << 7)] = vi[i];
        }
        if (t > 0) poll_own<1>(lmy, gmy, 2 * t, fb);  // B(t-1) done
        if (a0 && w < 4) {  // h0 rows
            const int bi = w;
            const float* hrow = h0b + (size_t)bi * HH;
            float2 vh[4];
            if (fb) {
#pragma unroll
                for (int i = 0; i < 4; ++i) vh[i] = ld2_sc1(hrow + kb + (i << 7));
            } else {
                ld2_sc0_x4(hrow + kb, hrow + kb + 128, hrow + kb + 256,
                           hrow + kb + 384, vh[0], vh[1], vh[2], vh[3]);
            }
#pragma unroll
            for (int i = 0; i < 4; ++i)
                *(float2*)&ldsA[0][bi][512 + kb + (i << 7)] = vh[i];
        }
        if (a1 && w >= 4) {  // y0 + h1 rows
            const int bi = w - 4;
            const float* yrow = y0g + (size_t)bi * HH;
            const float* hrow = h1b + (size_t)bi * HH;
            float2 vy[4], vh[4];
            if (fb) {
#pragma unroll
                for (int i = 0; i < 4; ++i) {
                    vy[i] = ld2_sc1(yrow + kb + (i << 7));
                    vh[i] = ld2_sc1(hrow + kb + (i << 7));
                }
            } else {
                ld2_sc0_x4(yrow + kb, yrow + kb + 128, yrow + kb + 256,
                           yrow + kb + 384, vy[0], vy[1], vy[2], vy[3]);
                ld2_sc0_x4(hrow + kb, hrow + kb + 128, hrow + kb + 256,
                           hrow + kb + 384, vh[0], vh[1], vh[2], vh[3]);
            }
#pragma unroll
            for (int i = 0; i < 4; ++i) {
                *(float2*)&ldsA[1][bi][kb + (i << 7)] = vy[i];
                *(float2*)&ldsA[1][bi][512 + kb + (i << 7)] = vh[i];
            }
        }
        __syncthreads();
        if (a0) {
#pragma unroll
            for (int bi = 0; bi < 4; ++bi) {
                float2 q0 = {0.f, 0.f}, q1 = {0.f, 0.f}, q2 = {0.f, 0.f}, q3 = {0.f, 0.f};
#pragma unroll
                for (int i = 0; i < 8; ++i) {
                    const float2 v = *(const float2*)&ldsA[0][bi][kb + (i << 7)];
                    q0 = pkfma(v, wg0[0][i], q0);
                    q1 = pkfma(v, wg0[1][i], q1);
                    q2 = pkfma(v, wg0[2][i], q2);
                    q3 = pkfma(v, wg0[3][i], q3);
                }
                const float sum = red4(q0.x + q0.y, q1.x + q1.y,
                                       q2.x + q2.y, q3.x + q3.y, lane);
                if (lane < 4) {
                    const int j = gj0 + lane;
                    const float gg = 1.0f / (1.0f + __expf(-(sum + bg0)));
                    if (gj0 < HH) {
                        const float val = gg * ldsA[0][bi][512 + j];
                        if (fb) st1_sc1(rh0 + (size_t)bi * HH + j, val);
                        else rh0[(size_t)bi * HH + j] = val;
                    } else {
                        if (fb) st1_sc1(uu0 + (size_t)bi * HH + (j - HH), gg);
                        else uu0[(size_t)bi * HH + (j - HH)] = gg;
                    }
                }
            }
        }
        if (a1) {
#pragma unroll
            for (int bi = 0; bi < 4; ++bi) {
                float2 q0 = {0.f, 0.f}, q1 = {0.f, 0.f}, q2 = {0.f, 0.f}, q3 = {0.f, 0.f};
#pragma unroll
                for (int i = 0; i < 8; ++i) {
                    const float2 v = *(const float2*)&ldsA[1][bi][kb + (i << 7)];
                    q0 = pkfma(v, wg1[0][i], q0);
                    q1 = pkfma(v, wg1[1][i], q1);
                    q2 = pkfma(v, wg1[2][i], q2);
                    q3 = pkfma(v, wg1[3][i], q3);
                }
                const float sum = red4(q0.x + q0.y, q1.x + q1.y,
                                       q2.x + q2.y, q3.x + q3.y, lane);
                if (lane < 4) {
                    const int j = gj0 + lane;
                    const float gg = 1.0f / (1.0f + __expf(-(sum + bg1)));
                    if (gj0 < HH) {
                        const float val = gg * ldsA[1][bi][512 + j];
                        if (fb) st1_sc1(rh1 + (size_t)bi * HH + j, val);
                        else rh1[(size_t)bi * HH + j] = val;
                    } else {
                        if (fb) st1_sc1(uu1 + (size_t)bi * HH + (j - HH), gg);
                        else uu1[(size_t)bi * HH + (j - HH)] = gg;
                    }
                }
            }
        }
        arrive(&lmy[slot], &gmy[slot], 2 * t + 1, fb);

        // ================= phase B: cand + update (both layers) =================
        poll_own<1>(lmy, gmy, 2 * t + 1, fb);  // A(t) done
        if (a0 && w < 4) {
            const int bi = w;
            const float* rrow = rh0 + (size_t)bi * HH;
            float2 vr[4];
            if (fb) {
#pragma unroll
                for (int i = 0; i < 4; ++i) vr[i] = ld2_sc1(rrow + kb + (i << 7));
            } else {
                ld2_sc0_x4(rrow + kb, rrow + kb + 128, rrow + kb + 256,
                           rrow + kb + 384, vr[0], vr[1], vr[2], vr[3]);
            }
#pragma unroll
            for (int i = 0; i < 4; ++i)
                *(float2*)&ldsB[0][bi][kb + (i << 7)] = vr[i];
            if (lane < 16) {
                const float* up = uu0 + (size_t)bi * HH + slot * 16 + lane;
                ldsU[0][bi][lane] = fb ? ld1f_sc1(up) : ld_sc0f(up);
            }
        }
        if (a1 && w >= 4) {
            const int bi = w - 4;
            const float* rrow = rh1 + (size_t)bi * HH;
            float2 vr[4];
            if (fb) {
#pragma unroll
                for (int i = 0; i < 4; ++i) vr[i] = ld2_sc1(rrow + kb + (i << 7));
            } else {
                ld2_sc0_x4(rrow + kb, rrow + kb + 128, rrow + kb + 256,
                           rrow + kb + 384, vr[0], vr[1], vr[2], vr[3]);
            }
#pragma unroll
            for (int i = 0; i < 4; ++i)
                *(float2*)&ldsB[1][bi][kb + (i << 7)] = vr[i];
            if (lane < 16) {
                const float* up = uu1 + (size_t)bi * HH + slot * 16 + lane;
                ldsU[1][bi][lane] = fb ? ld1f_sc1(up) : ld_sc0f(up);
            }
        }
        __syncthreads();
        if (a0) {
#pragma unroll
            for (int bi = 0; bi < 4; ++bi) {
                float2 q0 = {0.f, 0.f}, q1 = {0.f, 0.f};
#pragma unroll
                for (int i = 0; i < 4; ++i) {
                    const float2 v = *(const float2*)&ldsA[0][bi][kb + (i << 7)];
                    q0 = pkfma(v, wc0[0][i], q0);
                    q1 = pkfma(v, wc0[1][i], q1);
                }
#pragma unroll
                for (int i = 0; i < 4; ++i) {
                    const float2 v = *(const float2*)&ldsB[0][bi][kb + (i << 7)];
                    q0 = pkfma(v, wc0[0][i + 4], q0);
                    q1 = pkfma(v, wc0[1][i + 4], q1);
                }
                const float sum = red2(q0.x + q0.y, q1.x + q1.y, lane);
                if (lane < 2) {
                    const int m = cm0 + lane;
                    const float cv = tanhf(sum + bc0);
                    const float u = ldsU[0][bi][w * 2 + lane];
                    const float hold = ldsA[0][bi][512 + m];
                    const bool actm = t < sl_[bi];
                    const float hn = u * hold + (1.0f - u) * cv;
                    const float hst = actm ? hn : hold;
                    const float yv = actm ? hn : 0.0f;
                    if (fb) {
                        st1_sc1(h0b + (size_t)bi * HH + m, hst);
                        st1_sc1(y0g + (size_t)bi * HH + m, yv);
                    } else {
                        h0b[(size_t)bi * HH + m] = hst;
                        y0g[(size_t)bi * HH + m] = yv;
                    }
                }
            }
        }
        if (a1) {
#pragma unroll
            for (int bi = 0; bi < 4; ++bi) {
                float2 q0 = {0.f, 0.f}, q1 = {0.f, 0.f};
#pragma unroll
                for (int i = 0; i < 4; ++i) {
                    const float2 v = *(const float2*)&ldsA[1][bi][kb + (i << 7)];
                    q0 = pkfma(v, wc1[0][i], q0);
                    q1 = pkfma(v, wc1[1][i], q1);
                }
#pragma unroll
                for (int i = 0; i < 4; ++i) {
                    const float2 v = *(const float2*)&ldsB[1][bi][kb + (i << 7)];
                    q0 = pkfma(v, wc1[0][i + 4], q0);
                    q1 = pkfma(v, wc1[1][i + 4], q1);
                }
                const float sum = red2(q0.x + q0.y, q1.x + q1.y, lane);
                if (lane < 2) {
                    const int m = cm0 + lane;
                    const float cv = tanhf(sum + bc1);
                    const float u = ldsU[1][bi][w * 2 + lane];
                    const float hold = ldsA[1][bi][512 + m];
                    const bool actm = tt < sl_[bi];
                    const float hn = u * hold + (1.0f - u) * cv;
                    const float hst = actm ? hn : hold;
                    const float yv = actm ? hn : 0.0f;
                    if (fb) st1_sc1(h1b + (size_t)bi * HH + m, hst);
                    else h1b[(size_t)bi * HH + m] = hst;
                    out[((size_t)(b0 + bi) * TT + tt) * HH + m] = yv;
                }
            }
        }
        arrive(&lmy[slot], &gmy[slot], 2 * t + 2, fb);
    }
}

extern "C" void kernel_launch(void* const* d_in, const int* in_sizes, int n_in,
                              void* d_out, int out_size, void* d_ws, size_t ws_size,
                              hipStream_t stream) {
    const float* x = (const float*)d_in[0];
    const int* seq_lens = (const int*)d_in[1];
    const float* Wg = (const float*)d_in[2];
    const float* bg = (const float*)d_in[3];
    const float* Wc = (const float*)d_in[4];
    const float* bc = (const float*)d_in[5];
    float* out = (float*)d_out;
    float* ws = (float*)d_ws;

    // zero all state + control + flags; zero out (t >= T_g region & masked tail)
    (void)hipMemsetAsync(ws, 0, 115456 * sizeof(float), stream);
    (void)hipMemsetAsync(out, 0, (size_t)out_size * sizeof(float), stream);

    rnn_persist<<<NBLK, NTHR, 0, stream>>>(x, seq_lens, Wg, bg, Wc, bc, out, ws);
}

// Round 19
// 4484.655 us; speedup vs baseline: 2.5367x; 1.5573x over previous
//
#include <hip/hip_runtime.h>
#include <cstddef>

#define BB 32
#define TT 512
#define HH 512
#define NBLK 256
#define NTHR 512
#define YD 16  // y0 ring depth
#define AG __HIP_MEMORY_SCOPE_AGENT

// ---------------------------------------------------------------------------
// Persistent GRU, round 18 = round 13 (best verified: 5.79 ms) +
//   (1) fast activations: tanh = 1 - 2*rcp(exp(2x)+1), sigmoid = rcp(1+exp(-x))
//       (v_exp+v_rcp, ~1e-6 rel err; replaces ~100-instr libm tanhf),
//   (2) per-batch masked-step skip: guard every per-bi compute block with
//       the wave-uniform (t < seq_len[bi]) — dead work for frozen steps,
//   (3) group early-exit at Tg = max(group's seq_lens); out pre-zeroed.
// Sync skeleton byte-identical to round 13 (proven):
//   slot-as-progress sc1 flags; ballot polls; arrive = syncthreads (vmcnt
//   drain) + one sc1 store, every phase incl. last. Gates: L1 A(t): peer >=
//   2t+2 (max 2Tg = L0 final arrive); L0 B(t>=YD): peer >= 2t-31; own 2t/2t+1.
//   Data: XCD-local h/rh/uu plain stores + sc0 loads; cross-XCD y0 sc1;
//   x/W/b plain cached. Fallback (bad XCC map): all sc1.
// Masked-skip safety: skipped (bi,t) leave rh/uu/y0 stale; stale values are
// only read into computations that are themselves skipped or discarded
// (h frozen because its store is inside the guard). out for masked/after-Tg
// steps comes from the launcher memset.
//
// ws (floats): h0@0[16384] h1@16384[16384] ctrl(int)@32768[64]
//   barb(int)@32832[192] pslot(int)@33024[8 groups x 32]
//   (zero region ends @33280)
//   y0@36864[16][32][512] rh@299008[2][32][512] uu@331776[2][32][512]
// ---------------------------------------------------------------------------

__device__ __forceinline__ float2 ld2_sc1(const float* p) {
    double d = __hip_atomic_load((const double*)p, __ATOMIC_RELAXED, AG);
    return __builtin_bit_cast(float2, d);
}
__device__ __forceinline__ float ld1f_sc1(const float* p) {
    return __hip_atomic_load(p, __ATOMIC_RELAXED, AG);
}
__device__ __forceinline__ void st1_sc1(float* p, float v) {
    __hip_atomic_store(p, v, __ATOMIC_RELAXED, AG);
}
__device__ __forceinline__ int ldi_sc1(const int* p) {
    return __hip_atomic_load(p, __ATOMIC_RELAXED, AG);
}
__device__ __forceinline__ void sti_sc1(int* p, int v) {
    __hip_atomic_store(p, v, __ATOMIC_RELAXED, AG);
}

// v_rcp_f32: ~1ulp-of-2^-22 reciprocal, plenty for the 4.7e-3 budget.
__device__ __forceinline__ float frcp(float x) {
    float r;
    asm("v_rcp_f32 %0, %1" : "=v"(r) : "v"(x));
    return r;
}
// sigmoid(x) = rcp(1 + exp(-x))
__device__ __forceinline__ float fsig(float x) {
    return frcp(1.0f + __expf(-x));
}
// tanh(x) = 1 - 2*rcp(exp(2x)+1); saturates correctly at +-1.
__device__ __forceinline__ float ftanh(float x) {
    return fmaf(-2.0f, frcp(__expf(2.0f * x) + 1.0f), 1.0f);
}

// Packed f32 FMA: d = a*b + c on both halves, one instruction (r13-proven).
__device__ __forceinline__ float2 pkfma(float2 a, float2 b, float2 c) {
    float2 d;
    asm("v_pk_fma_f32 %0, %1, %2, %3" : "=v"(d) : "v"(a), "v"(b), "v"(c));
    return d;
}

// Scalar float load, L1-bypass / local-L2 hit (early-clobber dest, r16 fix).
__device__ __forceinline__ float ld_sc0f(const float* p) {
    float r;
    asm volatile("global_load_dword %0, %1, off sc0\n\ts_waitcnt vmcnt(0)"
                 : "=&v"(r) : "v"(p) : "memory");
    return r;
}

// Four 8B loads, L1-bypass / local-L2 hit, EARLY-CLOBBER outputs (r16 fix).
__device__ __forceinline__ void ld2_sc0_x4(const float* p0, const float* p1,
                                           const float* p2, const float* p3,
                                           float2& v0, float2& v1,
                                           float2& v2, float2& v3) {
    asm volatile(
        "global_load_dwordx2 %0, %4, off sc0\n\t"
        "global_load_dwordx2 %1, %5, off sc0\n\t"
        "global_load_dwordx2 %2, %6, off sc0\n\t"
        "global_load_dwordx2 %3, %7, off sc0\n\t"
        "s_waitcnt vmcnt(0)"
        : "=&v"(v0), "=&v"(v1), "=&v"(v2), "=&v"(v3)
        : "v"(p0), "v"(p1), "v"(p2), "v"(p3)
        : "memory");
}

// Reduce 4 accs over 64 lanes; lane ends with total of acc[lane&3].
__device__ __forceinline__ float red4(float a0, float a1, float a2, float a3,
                                      int lane) {
    const bool b1 = lane & 1, b2 = lane & 2;
    float p0 = (b1 ? a1 : a0) + __shfl_xor((b1 ? a0 : a1), 1, 64);
    float p1 = (b1 ? a3 : a2) + __shfl_xor((b1 ? a2 : a3), 1, 64);
    float r = (b2 ? p1 : p0) + __shfl_xor((b2 ? p0 : p1), 2, 64);
    r += __shfl_xor(r, 4, 64);
    r += __shfl_xor(r, 8, 64);
    r += __shfl_xor(r, 16, 64);
    r += __shfl_xor(r, 32, 64);
    return r;
}
// Reduce 2 accs; lane ends with total of acc[lane&1].
__device__ __forceinline__ float red2(float a0, float a1, int lane) {
    const bool b1 = lane & 1;
    float r = (b1 ? a1 : a0) + __shfl_xor((b1 ? a0 : a1), 1, 64);
    r += __shfl_xor(r, 2, 64);
    r += __shfl_xor(r, 4, 64);
    r += __shfl_xor(r, 8, 64);
    r += __shfl_xor(r, 16, 64);
    r += __shfl_xor(r, 32, 64);
    return r;
}

// Global 2-level tree barrier (sc1 RMW) - prologue / self-org only (proven).
__device__ __forceinline__ void gbar(int* barb, int bid, int nbar) {
    __syncthreads();
    if (threadIdx.x == 0) {
        __hip_atomic_fetch_add(&barb[(bid & 31) * 4], 1, __ATOMIC_RELAXED, AG);
        if (bid < 32) {
            const int lt = nbar * 8;
            while (__hip_atomic_load(&barb[bid * 4], __ATOMIC_RELAXED, AG) < lt)
                __builtin_amdgcn_s_sleep(1);
            __hip_atomic_fetch_add(&barb[128], 1, __ATOMIC_RELAXED, AG);
        }
        const int rt = nbar * 32;
        while (__hip_atomic_load(&barb[128], __ATOMIC_RELAXED, AG) < rt)
            __builtin_amdgcn_s_sleep(1);
    }
    __syncthreads();
}

// Ballot-poll until ALL 32 slot words of `slots` reach `need`.
template <int SLP>
__device__ __forceinline__ void poll_slots(int* slots, int need) {
    if (threadIdx.x < 64) {
        for (;;) {
            const int v = __hip_atomic_load(&slots[threadIdx.x & 31],
                                            __ATOMIC_RELAXED, AG);
            if (__ballot(v >= need) == ~0ull) break;
            __builtin_amdgcn_s_sleep(SLP);
        }
    }
    __syncthreads();
}

// Arrive: drain this block's stores, then one sc1 store (no RMW).
__device__ __forceinline__ void arrive(int* myslot, int val) {
    __syncthreads();  // compiler drains vmcnt(0) before s_barrier
    if (threadIdx.x == 0) sti_sc1(myslot, val);
}

__global__ __launch_bounds__(NTHR, 2) void rnn_persist(
    const float* __restrict__ x, const int* __restrict__ seq_lens,
    const float* __restrict__ Wg, const float* __restrict__ bg,
    const float* __restrict__ Wc, const float* __restrict__ bc,
    float* __restrict__ out, float* __restrict__ ws) {
    __shared__ float ldsA[8][1024];  // per batch: [input 512 | h 512]
    __shared__ float ldsB[8][512];   // rh rows
    __shared__ float ldsU[8][16];    // u, block's own 16 cand cols only
    __shared__ int shi[4];

    float* h0 = ws;
    float* h1 = ws + 16384;
    int* ctrl = (int*)(ws + 32768);   // pools[16], order@16, fb@17, map@18..33
    int* barb = (int*)(ws + 32832);   // global tree (prologue only)
    int* pslot = (int*)(ws + 33024);  // 8 groups x 32 ints
    float* y0 = ws + 36864;           // [YD][BB][HH]
    float* rh = ws + 299008;
    float* uu = ws + 331776;

    const int tid = threadIdx.x, bid = blockIdx.x;
    const int w = tid >> 6, lane = tid & 63;

    // ---- self-organization by physical XCD (rounds 6/8/13 proven) ----
    if (tid == 0) {
        int xcc;
        asm volatile("s_getreg_b32 %0, hwreg(HW_REG_XCC_ID)" : "=s"(xcc));
        xcc &= 15;
        int slot = __hip_atomic_fetch_add(&ctrl[xcc], 1, __ATOMIC_RELAXED, AG);
        shi[0] = xcc; shi[1] = slot;
    }
    __syncthreads();
    gbar(barb, bid, 1);
    if (tid == 0) {
        if (ldi_sc1(&ctrl[shi[0]]) != 32)
            sti_sc1(&ctrl[17], 1);
        if (shi[1] == 0) {
            int ord = __hip_atomic_fetch_add(&ctrl[16], 1, __ATOMIC_RELAXED, AG);
            sti_sc1(&ctrl[18 + shi[0]], ord + 1);
        }
    }
    gbar(barb, bid, 2);
    if (tid == 0) {
        int fbf = ldi_sc1(&ctrl[17]);
        if (ldi_sc1(&ctrl[16]) != 8) fbf = 1;
        int xi, sl;
        if (fbf) { xi = bid & 7; sl = bid >> 3; }
        else     { xi = ldi_sc1(&ctrl[18 + shi[0]]) - 1; sl = shi[1]; }
        shi[2] = fbf; shi[3] = xi; shi[1] = sl;
    }
    __syncthreads();
    const int fb = shi[2];
    const int xcd = shi[3];   // logical group id 0..7
    const int slot = shi[1];  // 0..31 within group
    const int l = xcd & 1;
    const int g = xcd >> 1;
    const int b0 = g * 8;
    const int gj0 = slot * 32 + w * 4;
    const int cm0 = slot * 16 + w * 2;
    const int kb = 2 * lane;

    float* __restrict__ hl = l ? h1 : h0;
    float* __restrict__ rhl = rh + (size_t)l * (BB * HH);
    float* __restrict__ uul = uu + (size_t)l * (BB * HH);
    int* myslots = pslot + xcd * 32;
    int* peerslots = pslot + (g * 2 + (1 - l)) * 32;

    // ---- one-time weight load into registers (original layout) ----
    float2 wg[4][8];
#pragma unroll
    for (int c = 0; c < 4; ++c)
#pragma unroll
        for (int i = 0; i < 8; ++i) {
            const size_t r = (size_t)l * 1024 + kb + (i << 7);
            wg[c][i].x = Wg[r * 1024 + gj0 + c];
            wg[c][i].y = Wg[(r + 1) * 1024 + gj0 + c];
        }
    float2 wc[2][8];
#pragma unroll
    for (int c = 0; c < 2; ++c)
#pragma unroll
        for (int i = 0; i < 8; ++i) {
            const size_t r = (size_t)l * 1024 + kb + (i << 7);
            wc[c][i].x = Wc[r * 512 + cm0 + c];
            wc[c][i].y = Wc[(r + 1) * 512 + cm0 + c];
        }
    const float bgj = bg[l * 1024 + gj0 + (lane & 3)];
    const float bcm = bc[l * 512 + cm0 + (lane & 1)];
    int sl_[8];
#pragma unroll
    for (int i = 0; i < 8; ++i) sl_[i] = seq_lens[b0 + i];
    int Tg = sl_[0];
#pragma unroll
    for (int i = 1; i < 8; ++i) Tg = sl_[i] > Tg ? sl_[i] : Tg;

    for (int t = 0; t < Tg; ++t) {
        // ================= phase A: gates =================
        // L1 gate: y0[t] produced <=> all L0 slots >= 2t+2 (max 2Tg = final).
        if (l == 1) poll_slots<2>(peerslots, 2 * t + 2);
        {   // stage in-row of batch b0+w (no group dependency)
            const int b = b0 + w;
            const float* inrow = l ? (y0 + ((size_t)((t & (YD - 1)) * BB + b)) * HH)
                                   : (x + ((size_t)b * TT + t) * HH);
            float2 vi[4];
            if (l == 0) {
#pragma unroll
                for (int i = 0; i < 4; ++i)
                    vi[i] = *(const float2*)(inrow + kb + (i << 7));
            } else {
#pragma unroll
                for (int i = 0; i < 4; ++i)
                    vi[i] = ld2_sc1(inrow + kb + (i << 7));
            }
#pragma unroll
            for (int i = 0; i < 4; ++i)
                *(float2*)&ldsA[w][kb + (i << 7)] = vi[i];
        }
        __syncthreads();
        // in-half partial accs, packed — only for still-active batches
        float2 pA0[8], pA1[8], pA2[8], pA3[8];
#pragma unroll
        for (int bi = 0; bi < 8; ++bi) {
            if (t >= sl_[bi]) continue;  // wave-uniform skip (frozen batch)
            float2 q0 = {0.f, 0.f}, q1 = {0.f, 0.f}, q2 = {0.f, 0.f}, q3 = {0.f, 0.f};
#pragma unroll
            for (int i = 0; i < 4; ++i) {
                const float2 v = *(const float2*)&ldsA[bi][kb + (i << 7)];
                q0 = pkfma(v, wg[0][i], q0);
                q1 = pkfma(v, wg[1][i], q1);
                q2 = pkfma(v, wg[2][i], q2);
                q3 = pkfma(v, wg[3][i], q3);
            }
            pA0[bi] = q0; pA1[bi] = q1; pA2[bi] = q2; pA3[bi] = q3;
        }
        // wait end-of-B(t-1): h(t) complete, rh/uu(t-1) fully consumed
        if (t > 0) poll_slots<1>(myslots, 2 * t);
        {   // stage h-half of batch b0+w (fresh after wait)
            const int b = b0 + w;
            const float* hrow = hl + (size_t)b * HH;
            float2 vh[4];
            if (fb) {
#pragma unroll
                for (int i = 0; i < 4; ++i)
                    vh[i] = ld2_sc1(hrow + kb + (i << 7));
            } else {
                ld2_sc0_x4(hrow + kb, hrow + kb + 128, hrow + kb + 256,
                           hrow + kb + 384, vh[0], vh[1], vh[2], vh[3]);
            }
#pragma unroll
            for (int i = 0; i < 4; ++i)
                *(float2*)&ldsA[w][512 + kb + (i << 7)] = vh[i];
        }
        __syncthreads();
#pragma unroll
        for (int bi = 0; bi < 8; ++bi) {
            if (t >= sl_[bi]) continue;  // frozen batch: no gates, no stores
            float2 q0 = pA0[bi], q1 = pA1[bi], q2 = pA2[bi], q3 = pA3[bi];
#pragma unroll
            for (int i = 4; i < 8; ++i) {
                const float2 v = *(const float2*)&ldsA[bi][kb + (i << 7)];
                q0 = pkfma(v, wg[0][i], q0);
                q1 = pkfma(v, wg[1][i], q1);
                q2 = pkfma(v, wg[2][i], q2);
                q3 = pkfma(v, wg[3][i], q3);
            }
            const float sum = red4(q0.x + q0.y, q1.x + q1.y,
                                   q2.x + q2.y, q3.x + q3.y, lane);
            if (lane < 4) {
                const int j = gj0 + lane;
                const int b = b0 + bi;
                const float gg = fsig(sum + bgj);
                if (gj0 < HH) {
                    const float val = gg * ldsA[bi][512 + j];
                    if (fb) st1_sc1(rhl + (size_t)b * HH + j, val);
                    else rhl[(size_t)b * HH + j] = val;
                } else {
                    if (fb) st1_sc1(uul + (size_t)b * HH + (j - HH), gg);
                    else uul[(size_t)b * HH + (j - HH)] = gg;
                }
            }
        }
        arrive(&myslots[slot], 2 * t + 1);

        // ================= phase B: candidate + update =================
        // cand x-half partial accs, packed (active batches only)
        float2 pB0[8], pB1[8];
#pragma unroll
        for (int bi = 0; bi < 8; ++bi) {
            if (t >= sl_[bi]) continue;
            float2 q0 = {0.f, 0.f}, q1 = {0.f, 0.f};
#pragma unroll
            for (int i = 0; i < 4; ++i) {
                const float2 v = *(const float2*)&ldsA[bi][kb + (i << 7)];
                q0 = pkfma(v, wc[0][i], q0);
                q1 = pkfma(v, wc[1][i], q1);
            }
            pB0[bi] = q0; pB1[bi] = q1;
        }
        // wait end-of-A(t): rh/uu(t) complete, h(t) fully consumed
        poll_slots<1>(myslots, 2 * t + 1);
        // L0 ring gate: L1 consumed y0[t-16] <=> all L1 slots >= 2t-31.
        if (l == 0 && t >= YD) poll_slots<2>(peerslots, 2 * t - 31);
        {   // stage rh row (full, feeds the dot) + u (own 16 cols only)
            const int b = b0 + w;
            const float* rrow = rhl + (size_t)b * HH;
            float2 vr[4];
            if (fb) {
#pragma unroll
                for (int i = 0; i < 4; ++i)
                    vr[i] = ld2_sc1(rrow + kb + (i << 7));
                if (lane < 16)
                    ldsU[w][lane] = ld1f_sc1(uul + (size_t)b * HH + slot * 16 + lane);
            } else {
                ld2_sc0_x4(rrow + kb, rrow + kb + 128, rrow + kb + 256,
                           rrow + kb + 384, vr[0], vr[1], vr[2], vr[3]);
                if (lane < 16)
                    ldsU[w][lane] = ld_sc0f(uul + (size_t)b * HH + slot * 16 + lane);
            }
#pragma unroll
            for (int i = 0; i < 4; ++i)
                *(float2*)&ldsB[w][kb + (i << 7)] = vr[i];
        }
        __syncthreads();
#pragma unroll
        for (int bi = 0; bi < 8; ++bi) {
            if (t >= sl_[bi]) continue;  // frozen: h untouched, out pre-zeroed
            float2 q0 = pB0[bi], q1 = pB1[bi];
#pragma unroll
            for (int i = 0; i < 4; ++i) {
                const float2 v = *(const float2*)&ldsB[bi][kb + (i << 7)];
                q0 = pkfma(v, wc[0][i + 4], q0);
                q1 = pkfma(v, wc[1][i + 4], q1);
            }
            const float sum = red2(q0.x + q0.y, q1.x + q1.y, lane);
            if (lane < 2) {
                const int m = cm0 + lane;
                const int b = b0 + bi;
                const float cv = ftanh(sum + bcm);
                const float u = ldsU[bi][w * 2 + lane];
                const float hold = ldsA[bi][512 + m];
                const float hn = u * hold + (1.0f - u) * cv;
                if (fb) st1_sc1(hl + (size_t)b * HH + m, hn);
                else hl[(size_t)b * HH + m] = hn;
                if (l == 0)
                    st1_sc1(y0 + ((size_t)((t & (YD - 1)) * BB + b)) * HH + m, hn);
                else
                    out[((size_t)b * TT + t) * HH + m] = hn;
            }
        }
        arrive(&myslots[slot], 2 * t + 2);
    }
}

extern "C" void kernel_launch(void* const* d_in, const int* in_sizes, int n_in,
                              void* d_out, int out_size, void* d_ws, size_t ws_size,
                              hipStream_t stream) {
    const float* x = (const float*)d_in[0];
    const int* seq_lens = (const int*)d_in[1];
    const float* Wg = (const float*)d_in[2];
    const float* bg = (const float*)d_in[3];
    const float* Wc = (const float*)d_in[4];
    const float* bc = (const float*)d_in[5];
    float* out = (float*)d_out;
    float* ws = (float*)d_ws;

    // zero h0/h1 + ctrl + prologue tree + slots; pre-zero out (masked steps
    // and t >= per-group Tg are never written by the kernel).
    (void)hipMemsetAsync(ws, 0, 33280 * sizeof(float), stream);
    (void)hipMemsetAsync(out, 0, (size_t)out_size * sizeof(float), stream);

    rnn_persist<<<NBLK, NTHR, 0, stream>>>(x, seq_lens, Wg, bg, Wc, bc, out, ws);
}

// Round 21
// 4383.335 us; speedup vs baseline: 2.5953x; 1.0231x over previous
//
#include <hip/hip_runtime.h>
#include <cstddef>

#define BB 32
#define TT 512
#define HH 512
#define NBLK 256
#define NTHR 512
#define YD 16  // y0 ring depth
#define AG __HIP_MEMORY_SCOPE_AGENT

// ---------------------------------------------------------------------------
// Persistent GRU, round 20 = round 18 (best verified: 4.48 ms) + two
// critical-path cuts, sync design untouched:
//   (1) L0 ring gate batched: checked only every 8th step (t%8==0, t>=16)
//       with stricter threshold 2t-17 (covers t..t+7 by monotonicity;
//       reachable: L1 hitting 2t-17 needs L0>=2t-16, L0 has arrived 2t);
//       and moved BEFORE the cand x-half partials so it overlaps compute.
//   (2) L1 A-phase peer poll sleep 2 -> 1 (the pipeline coupling edge).
// Everything else identical to r18: fast activations (v_exp+v_rcp), per-
// batch masked-step skip, group early-exit at Tg, slot-as-progress sc1
// flags, ballot polls, split-phase overlap, XCD-local data protocol
// (plain stores + sc0 loads), sc1 y0 ring, all-sc1 fallback.
//
// ws (floats): h0@0[16384] h1@16384[16384] ctrl(int)@32768[64]
//   barb(int)@32832[192] pslot(int)@33024[8 groups x 32]
//   (zero region ends @33280)
//   y0@36864[16][32][512] rh@299008[2][32][512] uu@331776[2][32][512]
// ---------------------------------------------------------------------------

__device__ __forceinline__ float2 ld2_sc1(const float* p) {
    double d = __hip_atomic_load((const double*)p, __ATOMIC_RELAXED, AG);
    return __builtin_bit_cast(float2, d);
}
__device__ __forceinline__ float ld1f_sc1(const float* p) {
    return __hip_atomic_load(p, __ATOMIC_RELAXED, AG);
}
__device__ __forceinline__ void st1_sc1(float* p, float v) {
    __hip_atomic_store(p, v, __ATOMIC_RELAXED, AG);
}
__device__ __forceinline__ int ldi_sc1(const int* p) {
    return __hip_atomic_load(p, __ATOMIC_RELAXED, AG);
}
__device__ __forceinline__ void sti_sc1(int* p, int v) {
    __hip_atomic_store(p, v, __ATOMIC_RELAXED, AG);
}

// v_rcp_f32: fast reciprocal (r18-proven; err ~1e-6 << 4.7e-3 budget).
__device__ __forceinline__ float frcp(float x) {
    float r;
    asm("v_rcp_f32 %0, %1" : "=v"(r) : "v"(x));
    return r;
}
__device__ __forceinline__ float fsig(float x) { return frcp(1.0f + __expf(-x)); }
__device__ __forceinline__ float ftanh(float x) {
    return fmaf(-2.0f, frcp(__expf(2.0f * x) + 1.0f), 1.0f);
}

// Packed f32 FMA: 2 FMAs in one instruction (r13-proven).
__device__ __forceinline__ float2 pkfma(float2 a, float2 b, float2 c) {
    float2 d;
    asm("v_pk_fma_f32 %0, %1, %2, %3" : "=v"(d) : "v"(a), "v"(b), "v"(c));
    return d;
}

// Scalar float load, L1-bypass / local-L2 hit (early-clobber dest, r16 fix).
__device__ __forceinline__ float ld_sc0f(const float* p) {
    float r;
    asm volatile("global_load_dword %0, %1, off sc0\n\ts_waitcnt vmcnt(0)"
                 : "=&v"(r) : "v"(p) : "memory");
    return r;
}

// Four 8B loads, L1-bypass / local-L2 hit, EARLY-CLOBBER outputs (r16 fix).
__device__ __forceinline__ void ld2_sc0_x4(const float* p0, const float* p1,
                                           const float* p2, const float* p3,
                                           float2& v0, float2& v1,
                                           float2& v2, float2& v3) {
    asm volatile(
        "global_load_dwordx2 %0, %4, off sc0\n\t"
        "global_load_dwordx2 %1, %5, off sc0\n\t"
        "global_load_dwordx2 %2, %6, off sc0\n\t"
        "global_load_dwordx2 %3, %7, off sc0\n\t"
        "s_waitcnt vmcnt(0)"
        : "=&v"(v0), "=&v"(v1), "=&v"(v2), "=&v"(v3)
        : "v"(p0), "v"(p1), "v"(p2), "v"(p3)
        : "memory");
}

// Reduce 4 accs over 64 lanes; lane ends with total of acc[lane&3].
__device__ __forceinline__ float red4(float a0, float a1, float a2, float a3,
                                      int lane) {
    const bool b1 = lane & 1, b2 = lane & 2;
    float p0 = (b1 ? a1 : a0) + __shfl_xor((b1 ? a0 : a1), 1, 64);
    float p1 = (b1 ? a3 : a2) + __shfl_xor((b1 ? a2 : a3), 1, 64);
    float r = (b2 ? p1 : p0) + __shfl_xor((b2 ? p0 : p1), 2, 64);
    r += __shfl_xor(r, 4, 64);
    r += __shfl_xor(r, 8, 64);
    r += __shfl_xor(r, 16, 64);
    r += __shfl_xor(r, 32, 64);
    return r;
}
// Reduce 2 accs; lane ends with total of acc[lane&1].
__device__ __forceinline__ float red2(float a0, float a1, int lane) {
    const bool b1 = lane & 1;
    float r = (b1 ? a1 : a0) + __shfl_xor((b1 ? a0 : a1), 1, 64);
    r += __shfl_xor(r, 2, 64);
    r += __shfl_xor(r, 4, 64);
    r += __shfl_xor(r, 8, 64);
    r += __shfl_xor(r, 16, 64);
    r += __shfl_xor(r, 32, 64);
    return r;
}

// Global 2-level tree barrier (sc1 RMW) - prologue / self-org only (proven).
__device__ __forceinline__ void gbar(int* barb, int bid, int nbar) {
    __syncthreads();
    if (threadIdx.x == 0) {
        __hip_atomic_fetch_add(&barb[(bid & 31) * 4], 1, __ATOMIC_RELAXED, AG);
        if (bid < 32) {
            const int lt = nbar * 8;
            while (__hip_atomic_load(&barb[bid * 4], __ATOMIC_RELAXED, AG) < lt)
                __builtin_amdgcn_s_sleep(1);
            __hip_atomic_fetch_add(&barb[128], 1, __ATOMIC_RELAXED, AG);
        }
        const int rt = nbar * 32;
        while (__hip_atomic_load(&barb[128], __ATOMIC_RELAXED, AG) < rt)
            __builtin_amdgcn_s_sleep(1);
    }
    __syncthreads();
}

// Ballot-poll until ALL 32 slot words of `slots` reach `need`.
template <int SLP>
__device__ __forceinline__ void poll_slots(int* slots, int need) {
    if (threadIdx.x < 64) {
        for (;;) {
            const int v = __hip_atomic_load(&slots[threadIdx.x & 31],
                                            __ATOMIC_RELAXED, AG);
            if (__ballot(v >= need) == ~0ull) break;
            __builtin_amdgcn_s_sleep(SLP);
        }
    }
    __syncthreads();
}

// Arrive: drain this block's stores, then one sc1 store (no RMW).
__device__ __forceinline__ void arrive(int* myslot, int val) {
    __syncthreads();  // compiler drains vmcnt(0) before s_barrier
    if (threadIdx.x == 0) sti_sc1(myslot, val);
}

__global__ __launch_bounds__(NTHR, 2) void rnn_persist(
    const float* __restrict__ x, const int* __restrict__ seq_lens,
    const float* __restrict__ Wg, const float* __restrict__ bg,
    const float* __restrict__ Wc, const float* __restrict__ bc,
    float* __restrict__ out, float* __restrict__ ws) {
    __shared__ float ldsA[8][1024];  // per batch: [input 512 | h 512]
    __shared__ float ldsB[8][512];   // rh rows
    __shared__ float ldsU[8][16];    // u, block's own 16 cand cols only
    __shared__ int shi[4];

    float* h0 = ws;
    float* h1 = ws + 16384;
    int* ctrl = (int*)(ws + 32768);   // pools[16], order@16, fb@17, map@18..33
    int* barb = (int*)(ws + 32832);   // global tree (prologue only)
    int* pslot = (int*)(ws + 33024);  // 8 groups x 32 ints
    float* y0 = ws + 36864;           // [YD][BB][HH]
    float* rh = ws + 299008;
    float* uu = ws + 331776;

    const int tid = threadIdx.x, bid = blockIdx.x;
    const int w = tid >> 6, lane = tid & 63;

    // ---- self-organization by physical XCD (rounds 6/8/13 proven) ----
    if (tid == 0) {
        int xcc;
        asm volatile("s_getreg_b32 %0, hwreg(HW_REG_XCC_ID)" : "=s"(xcc));
        xcc &= 15;
        int slot = __hip_atomic_fetch_add(&ctrl[xcc], 1, __ATOMIC_RELAXED, AG);
        shi[0] = xcc; shi[1] = slot;
    }
    __syncthreads();
    gbar(barb, bid, 1);
    if (tid == 0) {
        if (ldi_sc1(&ctrl[shi[0]]) != 32)
            sti_sc1(&ctrl[17], 1);
        if (shi[1] == 0) {
            int ord = __hip_atomic_fetch_add(&ctrl[16], 1, __ATOMIC_RELAXED, AG);
            sti_sc1(&ctrl[18 + shi[0]], ord + 1);
        }
    }
    gbar(barb, bid, 2);
    if (tid == 0) {
        int fbf = ldi_sc1(&ctrl[17]);
        if (ldi_sc1(&ctrl[16]) != 8) fbf = 1;
        int xi, sl;
        if (fbf) { xi = bid & 7; sl = bid >> 3; }
        else     { xi = ldi_sc1(&ctrl[18 + shi[0]]) - 1; sl = shi[1]; }
        shi[2] = fbf; shi[3] = xi; shi[1] = sl;
    }
    __syncthreads();
    const int fb = shi[2];
    const int xcd = shi[3];   // logical group id 0..7
    const int slot = shi[1];  // 0..31 within group
    const int l = xcd & 1;
    const int g = xcd >> 1;
    const int b0 = g * 8;
    const int gj0 = slot * 32 + w * 4;
    const int cm0 = slot * 16 + w * 2;
    const int kb = 2 * lane;

    float* __restrict__ hl = l ? h1 : h0;
    float* __restrict__ rhl = rh + (size_t)l * (BB * HH);
    float* __restrict__ uul = uu + (size_t)l * (BB * HH);
    int* myslots = pslot + xcd * 32;
    int* peerslots = pslot + (g * 2 + (1 - l)) * 32;

    // ---- one-time weight load into registers (original layout) ----
    float2 wg[4][8];
#pragma unroll
    for (int c = 0; c < 4; ++c)
#pragma unroll
        for (int i = 0; i < 8; ++i) {
            const size_t r = (size_t)l * 1024 + kb + (i << 7);
            wg[c][i].x = Wg[r * 1024 + gj0 + c];
            wg[c][i].y = Wg[(r + 1) * 1024 + gj0 + c];
        }
    float2 wc[2][8];
#pragma unroll
    for (int c = 0; c < 2; ++c)
#pragma unroll
        for (int i = 0; i < 8; ++i) {
            const size_t r = (size_t)l * 1024 + kb + (i << 7);
            wc[c][i].x = Wc[r * 512 + cm0 + c];
            wc[c][i].y = Wc[(r + 1) * 512 + cm0 + c];
        }
    const float bgj = bg[l * 1024 + gj0 + (lane & 3)];
    const float bcm = bc[l * 512 + cm0 + (lane & 1)];
    int sl_[8];
#pragma unroll
    for (int i = 0; i < 8; ++i) sl_[i] = seq_lens[b0 + i];
    int Tg = sl_[0];
#pragma unroll
    for (int i = 1; i < 8; ++i) Tg = sl_[i] > Tg ? sl_[i] : Tg;

    for (int t = 0; t < Tg; ++t) {
        // ================= phase A: gates =================
        // L1 gate: y0[t] produced <=> all L0 slots >= 2t+2 (max 2Tg = final).
        if (l == 1) poll_slots<1>(peerslots, 2 * t + 2);
        {   // stage in-row of batch b0+w (no group dependency)
            const int b = b0 + w;
            const float* inrow = l ? (y0 + ((size_t)((t & (YD - 1)) * BB + b)) * HH)
                                   : (x + ((size_t)b * TT + t) * HH);
            float2 vi[4];
            if (l == 0) {
#pragma unroll
                for (int i = 0; i < 4; ++i)
                    vi[i] = *(const float2*)(inrow + kb + (i << 7));
            } else {
#pragma unroll
                for (int i = 0; i < 4; ++i)
                    vi[i] = ld2_sc1(inrow + kb + (i << 7));
            }
#pragma unroll
            for (int i = 0; i < 4; ++i)
                *(float2*)&ldsA[w][kb + (i << 7)] = vi[i];
        }
        __syncthreads();
        // in-half partial accs, packed — only for still-active batches
        float2 pA0[8], pA1[8], pA2[8], pA3[8];
#pragma unroll
        for (int bi = 0; bi < 8; ++bi) {
            if (t >= sl_[bi]) continue;  // wave-uniform skip (frozen batch)
            float2 q0 = {0.f, 0.f}, q1 = {0.f, 0.f}, q2 = {0.f, 0.f}, q3 = {0.f, 0.f};
#pragma unroll
            for (int i = 0; i < 4; ++i) {
                const float2 v = *(const float2*)&ldsA[bi][kb + (i << 7)];
                q0 = pkfma(v, wg[0][i], q0);
                q1 = pkfma(v, wg[1][i], q1);
                q2 = pkfma(v, wg[2][i], q2);
                q3 = pkfma(v, wg[3][i], q3);
            }
            pA0[bi] = q0; pA1[bi] = q1; pA2[bi] = q2; pA3[bi] = q3;
        }
        // wait end-of-B(t-1): h(t) complete, rh/uu(t-1) fully consumed
        if (t > 0) poll_slots<1>(myslots, 2 * t);
        {   // stage h-half of batch b0+w (fresh after wait)
            const int b = b0 + w;
            const float* hrow = hl + (size_t)b * HH;
            float2 vh[4];
            if (fb) {
#pragma unroll
                for (int i = 0; i < 4; ++i)
                    vh[i] = ld2_sc1(hrow + kb + (i << 7));
            } else {
                ld2_sc0_x4(hrow + kb, hrow + kb + 128, hrow + kb + 256,
                           hrow + kb + 384, vh[0], vh[1], vh[2], vh[3]);
            }
#pragma unroll
            for (int i = 0; i < 4; ++i)
                *(float2*)&ldsA[w][512 + kb + (i << 7)] = vh[i];
        }
        __syncthreads();
#pragma unroll
        for (int bi = 0; bi < 8; ++bi) {
            if (t >= sl_[bi]) continue;  // frozen batch: no gates, no stores
            float2 q0 = pA0[bi], q1 = pA1[bi], q2 = pA2[bi], q3 = pA3[bi];
#pragma unroll
            for (int i = 4; i < 8; ++i) {
                const float2 v = *(const float2*)&ldsA[bi][kb + (i << 7)];
                q0 = pkfma(v, wg[0][i], q0);
                q1 = pkfma(v, wg[1][i], q1);
                q2 = pkfma(v, wg[2][i], q2);
                q3 = pkfma(v, wg[3][i], q3);
            }
            const float sum = red4(q0.x + q0.y, q1.x + q1.y,
                                   q2.x + q2.y, q3.x + q3.y, lane);
            if (lane < 4) {
                const int j = gj0 + lane;
                const int b = b0 + bi;
                const float gg = fsig(sum + bgj);
                if (gj0 < HH) {
                    const float val = gg * ldsA[bi][512 + j];
                    if (fb) st1_sc1(rhl + (size_t)b * HH + j, val);
                    else rhl[(size_t)b * HH + j] = val;
                } else {
                    if (fb) st1_sc1(uul + (size_t)b * HH + (j - HH), gg);
                    else uul[(size_t)b * HH + (j - HH)] = gg;
                }
            }
        }
        arrive(&myslots[slot], 2 * t + 1);

        // ================= phase B: candidate + update =================
        // L0 ring gate, BATCHED: every 8th step, stricter threshold 2t-17
        // covers steps t..t+7 (monotone); reachable (L1 at 2t-17 needs
        // L0 >= 2t-16, and L0 has arrived 2t). Placed here to overlap the
        // cand x-half partials below.
        if (l == 0 && t >= YD && (t & 7) == 0)
            poll_slots<1>(peerslots, 2 * t - 17);
        // cand x-half partial accs, packed (active batches only)
        float2 pB0[8], pB1[8];
#pragma unroll
        for (int bi = 0; bi < 8; ++bi) {
            if (t >= sl_[bi]) continue;
            float2 q0 = {0.f, 0.f}, q1 = {0.f, 0.f};
#pragma unroll
            for (int i = 0; i < 4; ++i) {
                const float2 v = *(const float2*)&ldsA[bi][kb + (i << 7)];
                q0 = pkfma(v, wc[0][i], q0);
                q1 = pkfma(v, wc[1][i], q1);
            }
            pB0[bi] = q0; pB1[bi] = q1;
        }
        // wait end-of-A(t): rh/uu(t) complete, h(t) fully consumed
        poll_slots<1>(myslots, 2 * t + 1);
        {   // stage rh row (full, feeds the dot) + u (own 16 cols only)
            const int b = b0 + w;
            const float* rrow = rhl + (size_t)b * HH;
            float2 vr[4];
            if (fb) {
#pragma unroll
                for (int i = 0; i < 4; ++i)
                    vr[i] = ld2_sc1(rrow + kb + (i << 7));
                if (lane < 16)
                    ldsU[w][lane] = ld1f_sc1(uul + (size_t)b * HH + slot * 16 + lane);
            } else {
                ld2_sc0_x4(rrow + kb, rrow + kb + 128, rrow + kb + 256,
                           rrow + kb + 384, vr[0], vr[1], vr[2], vr[3]);
                if (lane < 16)
                    ldsU[w][lane] = ld_sc0f(uul + (size_t)b * HH + slot * 16 + lane);
            }
#pragma unroll
            for (int i = 0; i < 4; ++i)
                *(float2*)&ldsB[w][kb + (i << 7)] = vr[i];
        }
        __syncthreads();
#pragma unroll
        for (int bi = 0; bi < 8; ++bi) {
            if (t >= sl_[bi]) continue;  // frozen: h untouched, out pre-zeroed
            float2 q0 = pB0[bi], q1 = pB1[bi];
#pragma unroll
            for (int i = 0; i < 4; ++i) {
                const float2 v = *(const float2*)&ldsB[bi][kb + (i << 7)];
                q0 = pkfma(v, wc[0][i + 4], q0);
                q1 = pkfma(v, wc[1][i + 4], q1);
            }
            const float sum = red2(q0.x + q0.y, q1.x + q1.y, lane);
            if (lane < 2) {
                const int m = cm0 + lane;
                const int b = b0 + bi;
                const float cv = ftanh(sum + bcm);
                const float u = ldsU[bi][w * 2 + lane];
                const float hold = ldsA[bi][512 + m];
                const float hn = u * hold + (1.0f - u) * cv;
                if (fb) st1_sc1(hl + (size_t)b * HH + m, hn);
                else hl[(size_t)b * HH + m] = hn;
                if (l == 0)
                    st1_sc1(y0 + ((size_t)((t & (YD - 1)) * BB + b)) * HH + m, hn);
                else
                    out[((size_t)b * TT + t) * HH + m] = hn;
            }
        }
        arrive(&myslots[slot], 2 * t + 2);
    }
}

extern "C" void kernel_launch(void* const* d_in, const int* in_sizes, int n_in,
                              void* d_out, int out_size, void* d_ws, size_t ws_size,
                              hipStream_t stream) {
    const float* x = (const float*)d_in[0];
    const int* seq_lens = (const int*)d_in[1];
    const float* Wg = (const float*)d_in[2];
    const float* bg = (const float*)d_in[3];
    const float* Wc = (const float*)d_in[4];
    const float* bc = (const float*)d_in[5];
    float* out = (float*)d_out;
    float* ws = (float*)d_ws;

    // zero h0/h1 + ctrl + prologue tree + slots; pre-zero out (masked steps
    // and t >= per-group Tg are never written by the kernel).
    (void)hipMemsetAsync(ws, 0, 33280 * sizeof(float), stream);
    (void)hipMemsetAsync(out, 0, (size_t)out_size * sizeof(float), stream);

    rnn_persist<<<NBLK, NTHR, 0, stream>>>(x, seq_lens, Wg, bg, Wc, bc, out, ws);
}